// Round 3
// baseline (122.176 us; speedup 1.0000x reference)
//
#include <hip/hip_runtime.h>
#include <hip/hip_bf16.h>
#include <math.h>

#define D 40
#define DIN 128
#define S 2048
#define B 8
#define NROWS (B*S)   // 16384
#define DP 64         // padded depth for Q/K bf16
#define DV 48         // padded depth for V bf16
#define PSTR 56       // P LDS row stride in ushorts

typedef __bf16 bf16x8 __attribute__((ext_vector_type(8)));
typedef float f32x4 __attribute__((ext_vector_type(4)));

static __device__ __forceinline__ unsigned short f2bf(float f) {
    unsigned u = __builtin_bit_cast(unsigned, f);
    u += 0x7fff + ((u >> 16) & 1);   // RNE
    return (unsigned short)(u >> 16);
}
static __device__ __forceinline__ bf16x8 ldfrag(const unsigned short* p) {
    return __builtin_bit_cast(bf16x8, *(const uint4*)p);
}

// ---------------- Kernel 1: adapter + rmsnorm + QKV (bf16 outputs) ----------------
// No in-loop __syncthreads: sE/sH slices are wave-private; within-wave LDS
// ordering is enforced by compiler lgkmcnt waits on the data dependences.
__global__ __launch_bounds__(256) void k1_adapter_qkv(
    const float* __restrict__ embs, const float* __restrict__ Wa,
    const float* __restrict__ ba, const float* __restrict__ ln1,
    const float* __restrict__ Wq, const float* __restrict__ Wk, const float* __restrict__ Wv,
    float* __restrict__ x, unsigned short* __restrict__ qb,
    unsigned short* __restrict__ kbq, unsigned short* __restrict__ vT)
{
    __shared__ float sWa[DIN*D];
    __shared__ float sWq[D*D], sWk[D*D], sWv[D*D];
    __shared__ float sba[D], sln[D];
    __shared__ float sE[4][DIN];
    __shared__ float sH[4][D];

    int tid = threadIdx.x;
    for (int i = tid; i < DIN*D; i += 256) sWa[i] = Wa[i];
    for (int i = tid; i < D*D; i += 256) { sWq[i]=Wq[i]; sWk[i]=Wk[i]; sWv[i]=Wv[i]; }
    if (tid < D) { sba[tid]=ba[tid]; sln[tid]=ln1[tid]; }
    __syncthreads();

    int wave = tid >> 6, lane = tid & 63;
    int base = blockIdx.x * 16;

    for (int it = 0; it < 4; ++it) {
        int row = base + it*4 + wave;
        sE[wave][lane]      = embs[row*DIN + lane];
        sE[wave][lane + 64] = embs[row*DIN + lane + 64];

        float xj = 0.f;
        if (lane < D) {
            float acc = sba[lane];
            const float4* e4 = (const float4*)&sE[wave][0];
            #pragma unroll
            for (int i = 0; i < DIN/4; ++i) {
                float4 e = e4[i];
                acc += e.x * sWa[(4*i+0)*D + lane];
                acc += e.y * sWa[(4*i+1)*D + lane];
                acc += e.z * sWa[(4*i+2)*D + lane];
                acc += e.w * sWa[(4*i+3)*D + lane];
            }
            xj = fmaxf(acc, 0.f);
            x[row*D + lane] = xj;
        }
        float ss = xj * xj;
        #pragma unroll
        for (int off = 32; off; off >>= 1) ss += __shfl_down(ss, off);
        ss = __shfl(ss, 0);
        float inv = rsqrtf(ss * (1.0f/D) + 1e-6f);
        if (lane < D) sH[wave][lane] = xj * inv * sln[lane];

        float aq = 0.f, ak = 0.f, av = 0.f;
        if (lane < D) {
            const float4* h4 = (const float4*)&sH[wave][0];
            #pragma unroll
            for (int i = 0; i < D/4; ++i) {
                float4 h = h4[i];
                aq += h.x*sWq[(4*i+0)*D+lane] + h.y*sWq[(4*i+1)*D+lane]
                    + h.z*sWq[(4*i+2)*D+lane] + h.w*sWq[(4*i+3)*D+lane];
                ak += h.x*sWk[(4*i+0)*D+lane] + h.y*sWk[(4*i+1)*D+lane]
                    + h.z*sWk[(4*i+2)*D+lane] + h.w*sWk[(4*i+3)*D+lane];
                av += h.x*sWv[(4*i+0)*D+lane] + h.y*sWv[(4*i+1)*D+lane]
                    + h.z*sWv[(4*i+2)*D+lane] + h.w*sWv[(4*i+3)*D+lane];
            }
        }
        qb [row*DP + lane] = (lane < D) ? f2bf(aq) : (unsigned short)0;
        kbq[row*DP + lane] = (lane < D) ? f2bf(ak) : (unsigned short)0;
        if (lane < D) vT[(size_t)lane*NROWS + row] = f2bf(av);
    }
}

// ---------------- Kernel 2: relative-position bias table ----------------
__global__ void k2_bias_table(const float* __restrict__ rel_bias, float* __restrict__ btab)
{
    int t = blockIdx.x * 256 + threadIdx.x;
    if (t >= 2*S - 1) return;
    int rel = t - (S - 1);          // rel = k - q
    int bucket = (rel > 0) ? 16 : 0;
    int ar = rel < 0 ? -rel : rel;
    int add;
    if (ar < 8) {
        add = ar;
    } else {
        float tt = logf((float)ar * 0.125f) / logf(16.0f) * 8.0f;
        int lg = 8 + (int)tt;
        add = lg < 15 ? lg : 15;
    }
    btab[t] = rel_bias[bucket + add];
}

// ---------------- Kernel 3: flash attention, MFMA bf16, split-K partials ----------------
// grid (S/64, B, NSPLIT). Each block: 64 q-rows, klen k-positions starting at
// blockIdx.z*klen. Emits unnormalized partial O and partial l (no-max softmax
// => partials combine linearly in k4).
__global__ __launch_bounds__(256) void k3_attn_mfma(
    const unsigned short* __restrict__ qb, const unsigned short* __restrict__ kb,
    const unsigned short* __restrict__ vT, const float* __restrict__ btab,
    float* __restrict__ po, float* __restrict__ pl, int klen)
{
    __shared__ float sbtw[2176];                 // bias window: klen+64 <= 2112
    __shared__ unsigned short sP[4][2][16*PSTR]; // ping-pong P per wave

    const int q0blk = blockIdx.x * 64;
    const int kt0   = blockIdx.z * klen;
    const int woff  = (S-1) + kt0 - q0blk - 63;

    int tid = threadIdx.x;
    for (int i = tid; i < klen + 64; i += 256) {
        int g = woff + i;
        sbtw[i] = btab[g < 0 ? 0 : (g > 4094 ? 4094 : g)];
    }
    __syncthreads();

    const int w  = tid >> 6, l = tid & 63;
    const int lr = l & 15,  lg = l >> 4;
    const int b  = blockIdx.y;
    const int q0 = q0blk + w * 16;

    const unsigned short* qrow = qb + ((size_t)(b*S) + q0 + lr) * DP + lg*8;
    const bf16x8 qf0 = ldfrag(qrow);
    const bf16x8 qf1 = ldfrag(qrow + 32);

    f32x4 of0 = {0,0,0,0}, of1 = {0,0,0,0}, of2 = {0,0,0,0};
    float el[4] = {0.f, 0.f, 0.f, 0.f};

    const unsigned short* kbase = kb + (size_t)(b*S)*DP + (size_t)lr*DP + lg*8;
    const unsigned short* vbase = vT + (size_t)lr*NROWS + (size_t)b*S + lg*8;
    const int ib0 = 63 - w*16 - lg*4 - kt0;      // + kt + lr at use site

    bf16x8 kfA[4], vfA[3], kfB[4], vfB[3];

    auto loadK = [&](int kt, bf16x8* kf) {
        const unsigned short* p = kbase + (size_t)kt*DP;
        kf[0] = ldfrag(p);         kf[1] = ldfrag(p + 32);
        kf[2] = ldfrag(p + 16*DP); kf[3] = ldfrag(p + 16*DP + 32);
    };
    auto loadV = [&](int kt, bf16x8* vf) {
        const unsigned short* p = vbase + kt;
        vf[0] = ldfrag(p);
        vf[1] = ldfrag(p + (size_t)16*NROWS);
        vf[2] = ldfrag(p + (size_t)32*NROWS);
    };

    auto compute = [&](int kt, const bf16x8* kf, const bf16x8* vf, unsigned short* pw) {
        f32x4 z = {0,0,0,0};
        f32x4 sc0 = __builtin_amdgcn_mfma_f32_16x16x32_bf16(qf0, kf[0], z, 0,0,0);
        sc0 = __builtin_amdgcn_mfma_f32_16x16x32_bf16(qf1, kf[1], sc0, 0,0,0);
        f32x4 sc1 = __builtin_amdgcn_mfma_f32_16x16x32_bf16(qf0, kf[2], z, 0,0,0);
        sc1 = __builtin_amdgcn_mfma_f32_16x16x32_bf16(qf1, kf[3], sc1, 0,0,0);

        const int ib = ib0 + kt + lr;
        #pragma unroll
        for (int r = 0; r < 4; ++r) {
            float e0 = __expf(sc0[r] + sbtw[ib - r]);
            float e1 = __expf(sc1[r] + sbtw[ib + 16 - r]);
            el[r] += e0 + e1;
            pw[(lg*4+r)*PSTR + lr]      = f2bf(e0);
            pw[(lg*4+r)*PSTR + 16 + lr] = f2bf(e1);
        }
        asm volatile("s_waitcnt lgkmcnt(0)" ::: "memory");
        __builtin_amdgcn_sched_barrier(0);
        bf16x8 pf = *(const bf16x8*)(pw + lr*PSTR + lg*8);

        of0 = __builtin_amdgcn_mfma_f32_16x16x32_bf16(pf, vf[0], of0, 0,0,0);
        of1 = __builtin_amdgcn_mfma_f32_16x16x32_bf16(pf, vf[1], of1, 0,0,0);
        of2 = __builtin_amdgcn_mfma_f32_16x16x32_bf16(pf, vf[2], of2, 0,0,0);
    };

    unsigned short* pw0 = &sP[w][0][0];
    unsigned short* pw1 = &sP[w][1][0];

    loadK(kt0, kfA); loadV(kt0, vfA);
    for (int kt = kt0; kt < kt0 + klen; kt += 64) {
        loadK(kt+32, kfB); loadV(kt+32, vfB);
        compute(kt, kfA, vfA, pw0);
        if (kt + 64 < kt0 + klen) { loadK(kt+64, kfA); loadV(kt+64, vfA); }
        compute(kt+32, kfB, vfB, pw1);
    }

    #pragma unroll
    for (int r = 0; r < 4; ++r) {
        float v = el[r];
        v += __shfl_xor(v, 1); v += __shfl_xor(v, 2);
        v += __shfl_xor(v, 4); v += __shfl_xor(v, 8);
        el[r] = v;
    }
    const size_t prow0 = (size_t)blockIdx.z * NROWS + b*S + q0 + lg*4;
    #pragma unroll
    for (int r = 0; r < 4; ++r) {
        float* pr = po + (prow0 + r) * D;
        pr[lr]      = of0[r];
        pr[16 + lr] = of1[r];
        if (lr < 8) pr[32 + lr] = of2[r];
        if (lr == 0) pl[prow0 + r] = el[r];
    }
}

// ---------------- Kernel 4: split-K combine + O-proj + residual + FF + rmsnorm ----------------
__global__ __launch_bounds__(256) void k4_out_ff(
    const float* __restrict__ x, const float* __restrict__ po, const float* __restrict__ pl,
    const float* __restrict__ Wo, const float* __restrict__ ln2,
    const float* __restrict__ wi, const float* __restrict__ wo,
    const float* __restrict__ lnf, float* __restrict__ out, int nsplit)
{
    __shared__ float sWo[D*D], sWi[D*D], sWo2[D*D];
    __shared__ float sln2[D], slnf[D];
    __shared__ float sA[4][D], sB2[4][D];

    int tid = threadIdx.x;
    for (int i = tid; i < D*D; i += 256) { sWo[i]=Wo[i]; sWi[i]=wi[i]; sWo2[i]=wo[i]; }
    if (tid < D) { sln2[tid]=ln2[tid]; slnf[tid]=lnf[tid]; }
    __syncthreads();

    int wave = tid >> 6, lane = tid & 63;
    int base = blockIdx.x * 16;

    for (int it = 0; it < 4; ++it) {
        int row = base + it*4 + wave;

        // combine split-K partials
        float lsum = 0.f;
        for (int s = 0; s < nsplit; ++s) lsum += pl[(size_t)s*NROWS + row];
        float linv = 1.0f / lsum;
        if (lane < D) {
            float acc = 0.f;
            for (int s = 0; s < nsplit; ++s) acc += po[((size_t)s*NROWS + row)*D + lane];
            sA[wave][lane] = acc * linv;
        }

        float x2 = 0.f;
        if (lane < D) {
            float acc = 0.f;
            const float4* a4 = (const float4*)&sA[wave][0];
            #pragma unroll
            for (int i = 0; i < D/4; ++i) {
                float4 a = a4[i];
                acc += a.x*sWo[(4*i+0)*D+lane] + a.y*sWo[(4*i+1)*D+lane]
                     + a.z*sWo[(4*i+2)*D+lane] + a.w*sWo[(4*i+3)*D+lane];
            }
            x2 = x[row*D + lane] + acc;
        }
        float ss = x2 * x2;
        #pragma unroll
        for (int off = 32; off; off >>= 1) ss += __shfl_down(ss, off);
        ss = __shfl(ss, 0);
        float inv = rsqrtf(ss * (1.0f/D) + 1e-6f);
        if (lane < D) sB2[wave][lane] = x2 * inv * sln2[lane];

        float f1 = 0.f;
        if (lane < D) {
            float acc = 0.f;
            const float4* b4 = (const float4*)&sB2[wave][0];
            #pragma unroll
            for (int i = 0; i < D/4; ++i) {
                float4 h = b4[i];
                acc += h.x*sWi[(4*i+0)*D+lane] + h.y*sWi[(4*i+1)*D+lane]
                     + h.z*sWi[(4*i+2)*D+lane] + h.w*sWi[(4*i+3)*D+lane];
            }
            f1 = fmaxf(acc, 0.f);
            sA[wave][lane] = f1;
        }

        float x3 = 0.f;
        if (lane < D) {
            float acc = 0.f;
            const float4* a4 = (const float4*)&sA[wave][0];
            #pragma unroll
            for (int i = 0; i < D/4; ++i) {
                float4 h = a4[i];
                acc += h.x*sWo2[(4*i+0)*D+lane] + h.y*sWo2[(4*i+1)*D+lane]
                     + h.z*sWo2[(4*i+2)*D+lane] + h.w*sWo2[(4*i+3)*D+lane];
            }
            x3 = x2 + acc;
        }
        float ss2 = x3 * x3;
        #pragma unroll
        for (int off = 32; off; off >>= 1) ss2 += __shfl_down(ss2, off);
        ss2 = __shfl(ss2, 0);
        float inv2 = rsqrtf(ss2 * (1.0f/D) + 1e-6f);
        if (lane < D) out[row*D + lane] = x3 * inv2 * slnf[lane];
    }
}

extern "C" void kernel_launch(void* const* d_in, const int* in_sizes, int n_in,
                              void* d_out, int out_size, void* d_ws, size_t ws_size,
                              hipStream_t stream) {
    const float* embs = (const float*)d_in[0];
    const float* Wa   = (const float*)d_in[1];
    const float* ba   = (const float*)d_in[2];
    const float* ln1  = (const float*)d_in[3];
    const float* Wq   = (const float*)d_in[4];
    const float* Wk   = (const float*)d_in[5];
    const float* Wv   = (const float*)d_in[6];
    const float* Wo   = (const float*)d_in[7];
    const float* ln2  = (const float*)d_in[8];
    const float* wi   = (const float*)d_in[9];
    const float* wo   = (const float*)d_in[10];
    const float* lnf  = (const float*)d_in[11];
    const float* rb   = (const float*)d_in[12];

    char* wsb = (char*)d_ws;
    float*          x    = (float*)(wsb);                       // 2,621,440 B
    unsigned short* qb   = (unsigned short*)(wsb + 2621440);    // 2,097,152 B
    unsigned short* kbq  = (unsigned short*)(wsb + 4718592);    // 2,097,152 B
    unsigned short* vT   = (unsigned short*)(wsb + 6815744);    // 1,572,864 B
    float*          po   = (float*)(wsb + 8388608);             // nsplit*2,621,440 B
    // pl/btab placed after max po extent based on chosen nsplit

    // choose largest split-K factor that fits the workspace (ws_size is fixed
    // by the harness -> deterministic choice)
    int nsplit = 4;
    while (nsplit > 1 &&
           (size_t)8388608 + (size_t)nsplit*2621440 + (size_t)nsplit*65536 + 16384 > ws_size)
        nsplit >>= 1;
    float* pl   = (float*)(wsb + 8388608 + (size_t)nsplit*2621440);
    float* btab = (float*)(wsb + 8388608 + (size_t)nsplit*2621440 + (size_t)nsplit*65536);
    int klen = S / nsplit;

    // zero-pad V rows d=40..47
    (void)hipMemsetAsync(vT + (size_t)D*NROWS, 0, (size_t)(DV - D)*NROWS*2, stream);

    k1_adapter_qkv<<<NROWS/16, 256, 0, stream>>>(embs, Wa, ba, ln1, Wq, Wk, Wv, x, qb, kbq, vT);
    k2_bias_table<<<16, 256, 0, stream>>>(rb, btab);
    k3_attn_mfma<<<dim3(S/64, B, nsplit), 256, 0, stream>>>(qb, kbq, vT, btab, po, pl, klen);
    k4_out_ff<<<NROWS/16, 256, 0, stream>>>(x, po, pl, Wo, ln2, wi, wo, lnf, (float*)d_out, nsplit);
}